// Round 10
// baseline (91.617 us; speedup 1.0000x reference)
//
#include <hip/hip_runtime.h>
#include <math.h>

// LogicLayer: y[b,o] = prod_i ( a[b,i] + nw[o,i] - a[b,i]*nw[o,i] )
//   fw = sigmoid(W[o,i]) in (0,1) => neg-branch dead, abs() no-op.
//   term = 1 - (1-a)*fw = fma(a-1, fw, 1.0f).   am = a-1 staged in LDS.
// B=4096, OUT=256, IN=256, fp32.
//
// r10 == r9 (held stable; no hardware feedback yet, further blind mutation
// is negative-EV). Single template kernel, two instantiations as the A/B:
//   A: NOJ=8, grid 256 (1 blk/CU, 2 waves/SIMD) — LDS:VALU = 64:64 cy/quad
//   B: NOJ=4, grid 512 (2 blk/CU, 4 waves/SIMD) — LDS:VALU = 128:64 (LDS-hot)
// LDS = exactly 64KB: am[64][256] with 16B-unit XOR swizzle
// (unit' = unit ^ (row&7)) -> b128 reads/writes conflict-light (<=2-way).
// XCD remap: blocks sharing an atoms tile (same bb) land on one XCD.
// fw loads are wave-uniform (readfirstlane'd wave id) -> expect s_load.

#define IN_DIM 256
#define OUT_DIM 256
#define B_DIM 4096
#define BDIM 512
#define ROWS 64

typedef float v2f __attribute__((ext_vector_type(2)));

__device__ __forceinline__ v2f pk_fma(v2f a, v2f b, v2f c) {
#if __has_builtin(__builtin_elementwise_fma)
  return __builtin_elementwise_fma(a, b, c);  // llvm.fma.v2f32 -> v_pk_fma_f32
#else
  v2f r;
  r.x = fmaf(a.x, b.x, c.x);
  r.y = fmaf(a.y, b.y, c.y);
  return r;
#endif
}

__device__ __forceinline__ float sigmoidf_dev(float x) {
  if (x >= 0.0f) {
    return 1.0f / (1.0f + expf(-x));
  }
  const float e = expf(x);
  return e / (1.0f + e);
}

// ---- Kernel 1: fw[t] = sigmoid(W[t]), elementwise coalesced ----------------
__global__ __launch_bounds__(256) void sigmoid_ew(const float* __restrict__ w,
                                                  float* __restrict__ fw) {
  const int t = blockIdx.x * 256 + threadIdx.x;
  fw[t] = sigmoidf_dev(w[t]);
}

// ---- main kernel (templated A/B) -------------------------------------------
// NOJ_T: o's per thread. OBLOCKS_T = 256/(8*NOJ_T). MINW: min waves/EU hint.
template <int NOJ_T, int OBLOCKS_T, int MINW, bool SIG>
__global__ __launch_bounds__(BDIM, MINW) void logic_v(
    const float* __restrict__ atoms, const float* __restrict__ fw,
    float* __restrict__ out) {
  __shared__ float lds[ROWS * IN_DIM];  // 65536 B exactly; swizzled units

  const int t = threadIdx.x;

  // XCD-grouping remap (bijective): blocks with the same bb share an XCD so
  // the shared 64KB atoms tile is fetched from HBM once per XCD-L2.
  const int idx = blockIdx.x;
  const int xcd = idx & 7;
  const int local = idx >> 3;
  const int bb = xcd + 8 * (local / OBLOCKS_T);  // 0..63
  const int ob = local % OBLOCKS_T;
  const int b0 = bb * ROWS;

  // ---- stage am = atoms - 1 into LDS, 16B-unit XOR swizzle ----
  {
#pragma unroll
    for (int rnd = 0; rnd < 8; ++rnd) {
      const int e = rnd * 2048 + t * 4;  // linear element; wave covers 1 row
      const int row = e >> 8;
      const int lane_u = (e & 255) >> 2;          // unit within row, 0..63
      const int su = lane_u ^ (row & 7);          // swizzled unit
      const float4 v =
          *reinterpret_cast<const float4*>(atoms + (size_t)b0 * IN_DIM + e);
      float4 p;
      p.x = v.x - 1.0f;
      p.y = v.y - 1.0f;
      p.z = v.z - 1.0f;
      p.w = v.w - 1.0f;
      *reinterpret_cast<float4*>(&lds[row * IN_DIM + (su << 2)]) = p;
    }
  }
  __syncthreads();

  const int r = t & 63;  // lane = b-row
  const int w = __builtin_amdgcn_readfirstlane(t >> 6);  // uniform wave id
  const int rm = r & 7;                                  // swizzle mask
  const float* rowbase = lds + r * IN_DIM;
  const int ocol0 = ob * (8 * NOJ_T) + w * NOJ_T;
  const float* __restrict__ frow = fw + (size_t)ocol0 * IN_DIM;

  v2f prodv[NOJ_T];
#pragma unroll
  for (int j = 0; j < NOJ_T; ++j) prodv[j] = (v2f){1.0f, 1.0f};
  const v2f ones = {1.0f, 1.0f};

#pragma unroll 4
  for (int i = 0; i < IN_DIM; i += 4) {
    // swizzled b128 read of this lane's am quad (conflict-light)
    const float4 am4 = *reinterpret_cast<const float4*>(
        rowbase + ((((i >> 2) ^ rm)) << 2));
    v2f am01, am23;
    am01.x = am4.x; am01.y = am4.y;
    am23.x = am4.z; am23.y = am4.w;
#pragma unroll
    for (int j = 0; j < NOJ_T; ++j) {
      // wave-uniform address: compiler should emit s_load (SMEM) here.
      float4 f4 = *reinterpret_cast<const float4*>(frow + j * IN_DIM + i);
      if (SIG) {
        f4.x = sigmoidf_dev(f4.x);
        f4.y = sigmoidf_dev(f4.y);
        f4.z = sigmoidf_dev(f4.z);
        f4.w = sigmoidf_dev(f4.w);
      }
      v2f f01, f23;
      f01.x = f4.x; f01.y = f4.y;
      f23.x = f4.z; f23.y = f4.w;
      const v2f t01 = pk_fma(am01, f01, ones);
      const v2f t23 = pk_fma(am23, f23, ones);
      prodv[j] *= t01 * t23;
    }
  }

  // ---- epilogue: finish pair-products, vector-store NOJ_T floats ----
  float* op = out + (size_t)(b0 + r) * OUT_DIM + ocol0;
#pragma unroll
  for (int j0 = 0; j0 < NOJ_T; j0 += 4) {
    float4 s;
    s.x = prodv[j0 + 0].x * prodv[j0 + 0].y;
    s.y = prodv[j0 + 1].x * prodv[j0 + 1].y;
    s.z = prodv[j0 + 2].x * prodv[j0 + 2].y;
    s.w = prodv[j0 + 3].x * prodv[j0 + 3].y;
    *reinterpret_cast<float4*>(op + j0) = s;
  }
}

extern "C" void kernel_launch(void* const* d_in, const int* in_sizes, int n_in,
                              void* d_out, int out_size, void* d_ws,
                              size_t ws_size, hipStream_t stream) {
  const float* atoms = (const float*)d_in[0];    // [4096, 256]
  const float* weights = (const float*)d_in[1];  // [256, 256]
  float* out = (float*)d_out;                    // [4096, 256]

  if (ws_size >= (size_t)OUT_DIM * IN_DIM * sizeof(float)) {
    float* fw = (float*)d_ws;
    sigmoid_ew<<<dim3((OUT_DIM * IN_DIM) / 256), dim3(256), 0, stream>>>(
        weights, fw);
    // A/B in one bench. A: NOJ=8 (LDS-light, 2 waves/SIMD), grid 256.
    //                   B: NOJ=4 (LDS-hot, 4 waves/SIMD), grid 512.
    // B runs last and owns d_out for correctness.
    logic_v<8, 4, 2, false><<<dim3(64 * 4), dim3(BDIM), 0, stream>>>(
        atoms, fw, out);
    logic_v<4, 8, 4, false><<<dim3(64 * 8), dim3(BDIM), 0, stream>>>(
        atoms, fw, out);
  } else {
    // no workspace: inline sigmoid on W loads (same structure, B config)
    logic_v<4, 8, 4, true><<<dim3(64 * 8), dim3(BDIM), 0, stream>>>(
        atoms, weights, out);
  }
}